// Round 5
// baseline (8186.233 us; speedup 1.0000x reference)
//
#include <hip/hip_runtime.h>
#include <cmath>

typedef __bf16 bf16;
typedef float f32x4 __attribute__((ext_vector_type(4)));
typedef bf16 bf16x8 __attribute__((ext_vector_type(8)));
typedef bf16 bf16x2 __attribute__((ext_vector_type(2)));

#define DEVINL __device__ __forceinline__

DEVINL void gload_lds16(const void* g, void* l) {
  __builtin_amdgcn_global_load_lds(
      (const __attribute__((address_space(1))) void*)g,
      (__attribute__((address_space(3))) void*)l, 16, 0, 0);
}

DEVINL float sigf(float x) { return 1.f / (1.f + __expf(-x)); }

DEVINL bf16x8 as_bf16x8(f32x4 v) {
  union { f32x4 f; bf16x8 b; } u; u.f = v; return u.b;
}

// ---------------- fused prep: all weight casts + x prep + barrier zero ----------
__global__ void prep_all_k(
    const float* __restrict__ x,
    const float* __restrict__ eWih0, const float* __restrict__ eWhh0,
    const float* __restrict__ eWih1, const float* __restrict__ eWhh1,
    const float* __restrict__ dWih0, const float* __restrict__ dWhh0,
    const float* __restrict__ dWih1, const float* __restrict__ dWhh1,
    const float* __restrict__ fcW,
    bf16* __restrict__ Wih_e0, bf16* __restrict__ Whh_e0, bf16* __restrict__ Wcat_e1,
    bf16* __restrict__ Wih_d0, bf16* __restrict__ Whh_d0, bf16* __restrict__ Wcat_d1,
    bf16* __restrict__ Wfc, bf16* __restrict__ xe, bf16* __restrict__ xd,
    unsigned* __restrict__ bars) {
  int i = blockIdx.x * 256 + threadIdx.x;
  if (i == 0) { bars[0] = 0; bars[1] = 0; }
  if (i < 2097152) { Wih_e0[i] = (bf16)eWih0[i]; return; }
  i -= 2097152;
  if (i < 4194304) { Whh_e0[i] = (bf16)eWhh0[i]; return; }
  i -= 4194304;
  if (i < 8388608) {
    int k = i & 2047, r = i >> 11;
    Wcat_e1[i] = (bf16)((k < 1024) ? eWih1[r * 1024 + k] : eWhh1[r * 1024 + k - 1024]);
    return;
  }
  i -= 8388608;
  if (i < 2097152) { Wih_d0[i] = (bf16)dWih0[i]; return; }
  i -= 2097152;
  if (i < 4194304) { Whh_d0[i] = (bf16)dWhh0[i]; return; }
  i -= 4194304;
  if (i < 8388608) {
    int k = i & 2047, r = i >> 11;
    Wcat_d1[i] = (bf16)((k < 1024) ? dWih1[r * 1024 + k] : dWhh1[r * 1024 + k - 1024]);
    return;
  }
  i -= 8388608;
  if (i < 524288) { Wfc[i] = (bf16)fcW[i]; return; }
  i -= 524288;
  if (i < 4194304) {
    int ii = i & 511;
    int b = (i >> 9) & 63;
    int t = i >> 15;
    xe[i] = (bf16)x[b * 65536 + t * 512 + ii];
    xd[i] = (t == 0) ? (bf16)0.f : (bf16)x[b * 65536 + (t - 1) * 512 + ii];
  }
}

// ---------------- big GEMM: C[M,N] = A[M,K] @ W[N,K]^T (bf16 in, f32 acc) ----------
__global__ __launch_bounds__(256) void gemm_bt_k(
    const bf16* __restrict__ A, const bf16* __restrict__ Bw,
    bf16* __restrict__ Cbf, float* __restrict__ Cf32, const float* __restrict__ bias,
    int M, int N, int K, int mode) {
  __shared__ __attribute__((aligned(16))) bf16 As[128 * 32];
  __shared__ __attribute__((aligned(16))) bf16 Bs[128 * 32];
  const int tid = threadIdx.x;
  const int lane = tid & 63;
  const int wave = tid >> 6;
  const int wm = wave >> 1, wn = wave & 1;
  const int m0 = blockIdx.y * 128;
  const int n0 = blockIdx.x * 128;

  f32x4 acc[4][4];
  for (int i = 0; i < 4; ++i)
    for (int j = 0; j < 4; ++j) acc[i][j] = 0;

  const int r1 = tid >> 2;
  const int kc = (tid & 3) * 8;
  const int fr = lane & 15;
  const int fk = (lane >> 4) * 8;

  for (int k0 = 0; k0 < K; k0 += 32) {
    gload_lds16(A + (size_t)(m0 + r1) * K + k0 + kc, As + tid * 8);
    gload_lds16(A + (size_t)(m0 + 64 + r1) * K + k0 + kc, As + 2048 + tid * 8);
    gload_lds16(Bw + (size_t)(n0 + r1) * K + k0 + kc, Bs + tid * 8);
    gload_lds16(Bw + (size_t)(n0 + 64 + r1) * K + k0 + kc, Bs + 2048 + tid * 8);
    __syncthreads();
    bf16x8 af[4], bw[4];
    for (int i = 0; i < 4; ++i)
      af[i] = *(const bf16x8*)(As + (wm * 64 + i * 16 + fr) * 32 + fk);
    for (int j = 0; j < 4; ++j)
      bw[j] = *(const bf16x8*)(Bs + (wn * 64 + j * 16 + fr) * 32 + fk);
    for (int i = 0; i < 4; ++i)
      for (int j = 0; j < 4; ++j)
        acc[i][j] = __builtin_amdgcn_mfma_f32_16x16x32_bf16(af[i], bw[j], acc[i][j], 0, 0, 0);
    __syncthreads();
  }

  const int col16 = lane & 15;
  const int rq = (lane >> 4) * 4;
  for (int i = 0; i < 4; ++i)
    for (int j = 0; j < 4; ++j)
      for (int r = 0; r < 4; ++r) {
        int row = m0 + wm * 64 + i * 16 + rq + r;
        int col = n0 + wn * 64 + j * 16 + col16;
        float v = acc[i][j][r];
        if (mode == 0) {
          Cbf[(size_t)row * N + col] = (bf16)v;
        } else {
          v = sigf(v + bias[col]);
          int b = row & 63, t = row >> 6;
          Cf32[(size_t)b * (128 * 512) + (size_t)t * 512 + col] = v;
        }
      }
}

// ---------------- persistent two-layer phase kernel (cooperative) ----------------
// Same dataflow as R4 (validated), but weight fragments are PINNED in VGPRs via
// opaque asm after a one-time load: the compiler cannot rematerialize the loads
// inside the timestep loop (R4 showed VGPR_Count=48 -> weights re-fetched every
// step with ~3 loads in flight = the 26 us/step floor). Per-step memory work is
// now just the h-ring A-loads (independent dwordx4, deep MLP), G loads, one LDS
// reduce, one 4B agent-scope atomic store, one counter barrier.
__global__ __launch_bounds__(256, 1) void phase_k(
    const bf16* __restrict__ G, const bf16* __restrict__ WhhA,
    const float* __restrict__ biasA, const bf16* __restrict__ hA0,
    const float* __restrict__ cA0, bf16* __restrict__ RA,
    const bf16* __restrict__ WcatB, const float* __restrict__ biasB,
    const bf16* __restrict__ hB0, const float* __restrict__ cB0,
    bf16* __restrict__ RB, bf16* __restrict__ HfinA, bf16* __restrict__ HfinB,
    unsigned* __restrict__ bar) {
  __shared__ float gt[2][64][33];
  const int tid = threadIdx.x;
  const int lane = tid & 63;
  const int wave = tid >> 6;
  const int ct = wave & 1;
  const int kw = wave >> 1;
  const int half = blockIdx.x >> 7;
  const int j0 = (blockIdx.x & 127) * 8;
  const int fr = lane & 15;
  const int fk = (lane >> 4) * 8;
  const int rq = (lane >> 4) * 4;
  const int ccol = ct * 16 + fr;                          // gate-col 0..31
  const int nrow = (ccol >> 3) * 1024 + j0 + (ccol & 7);  // weight row
  const int cb = tid >> 2;                                // cell batch
  const int cj = (tid & 3) * 2;                           // cell col pair

  if (half == 0) {
    // =================== layer A: gates = G[t] + h@WhhA^T ===================
    f32x4 bw[16];
    {
      const bf16* wp = WhhA + (size_t)nrow * 1024 + kw * 512 + fk;
#pragma unroll
      for (int kk = 0; kk < 16; ++kk) bw[kk] = *(const f32x4*)(wp + kk * 32);
#pragma unroll
      for (int kk = 0; kk < 16; ++kk) asm volatile("" : "+v"(bw[kk]));
    }
    float bsr[4][2];
#pragma unroll
    for (int g = 0; g < 4; ++g) {
      bsr[g][0] = biasA[g * 1024 + j0 + cj];
      bsr[g][1] = biasA[g * 1024 + j0 + cj + 1];
    }
    float creg[2];
    if (cA0) {
      creg[0] = cA0[cb * 1024 + j0 + cj];
      creg[1] = cA0[cb * 1024 + j0 + cj + 1];
    } else {
      creg[0] = creg[1] = 0.f;
    }

    for (int d = 0; d <= 128; ++d) {
      if (d < 128) {
        const int t = d;
        const bf16* Gt = G + (size_t)t * 262144 + (size_t)cb * 4096;
        float gx[4][2];
#pragma unroll
        for (int g = 0; g < 4; ++g) {
          bf16x2 g2 = *(const bf16x2*)(Gt + g * 1024 + j0 + cj);
          gx[g][0] = (float)g2.x;
          gx[g][1] = (float)g2.y;
        }
        f32x4 acc[4];
        acc[0] = 0; acc[1] = 0; acc[2] = 0; acc[3] = 0;
        const bf16* hp = (t == 0) ? hA0 : (RA + (size_t)(t - 1) * 65536);
        if (hp) {
          const bf16* ap = hp + fr * 1024 + kw * 512 + fk;
#pragma unroll 8
          for (int kk = 0; kk < 16; ++kk) {
            bf16x8 a0 = *(const bf16x8*)(ap + kk * 32);
            bf16x8 a1 = *(const bf16x8*)(ap + 16384 + kk * 32);
            bf16x8 a2 = *(const bf16x8*)(ap + 32768 + kk * 32);
            bf16x8 a3 = *(const bf16x8*)(ap + 49152 + kk * 32);
            bf16x8 w = as_bf16x8(bw[kk]);
            acc[0] = __builtin_amdgcn_mfma_f32_16x16x32_bf16(a0, w, acc[0], 0, 0, 0);
            acc[1] = __builtin_amdgcn_mfma_f32_16x16x32_bf16(a1, w, acc[1], 0, 0, 0);
            acc[2] = __builtin_amdgcn_mfma_f32_16x16x32_bf16(a2, w, acc[2], 0, 0, 0);
            acc[3] = __builtin_amdgcn_mfma_f32_16x16x32_bf16(a3, w, acc[3], 0, 0, 0);
          }
        }
#pragma unroll
        for (int bt = 0; bt < 4; ++bt)
#pragma unroll
          for (int r = 0; r < 4; ++r)
            gt[kw][bt * 16 + rq + r][ct * 16 + fr] = acc[bt][r];
        __syncthreads();

        float hn[2];
#pragma unroll
        for (int r = 0; r < 2; ++r) {
          int jj = cj + r;
          float gi = gt[0][cb][jj]      + gt[1][cb][jj]      + gx[0][r] + bsr[0][r];
          float gf = gt[0][cb][8 + jj]  + gt[1][cb][8 + jj]  + gx[1][r] + bsr[1][r];
          float gg = gt[0][cb][16 + jj] + gt[1][cb][16 + jj] + gx[2][r] + bsr[2][r];
          float go = gt[0][cb][24 + jj] + gt[1][cb][24 + jj] + gx[3][r] + bsr[3][r];
          float cn = sigf(gf) * creg[r] + sigf(gi) * tanhf(gg);
          creg[r] = cn;
          hn[r] = sigf(go) * tanhf(cn);
        }
        union { bf16 h[2]; unsigned u; } pk;
        pk.h[0] = (bf16)hn[0];
        pk.h[1] = (bf16)hn[1];
        __hip_atomic_store((unsigned*)(RA + (size_t)t * 65536 + cb * 1024 + j0 + cj),
                           pk.u, __ATOMIC_RELAXED, __HIP_MEMORY_SCOPE_AGENT);
        if (HfinA && t == 127) {
          bf16x2 e2; e2.x = (bf16)tanhf(hn[0]); e2.y = (bf16)tanhf(hn[1]);
          *(bf16x2*)(HfinA + cb * 1024 + j0 + cj) = e2;
        }
      }
      __syncthreads();
      if (tid == 0) {
        __hip_atomic_fetch_add(bar, 1u, __ATOMIC_RELAXED, __HIP_MEMORY_SCOPE_AGENT);
        const unsigned tgt = (unsigned)(d + 1) * 256u;
        while (__hip_atomic_load(bar, __ATOMIC_RELAXED, __HIP_MEMORY_SCOPE_AGENT) < tgt)
          __builtin_amdgcn_s_sleep(2);
      }
      __syncthreads();
    }
  } else {
    // ============ layer B at t-1: gates = concat[RA[t], hB]@WcatB^T ============
    f32x4 bw[32];
    {
      const bf16* wp = WcatB + (size_t)nrow * 2048 + kw * 1024 + fk;
#pragma unroll
      for (int kk = 0; kk < 32; ++kk) bw[kk] = *(const f32x4*)(wp + kk * 32);
#pragma unroll
      for (int kk = 0; kk < 32; ++kk) asm volatile("" : "+v"(bw[kk]));
    }
    float bsr[4][2];
#pragma unroll
    for (int g = 0; g < 4; ++g) {
      bsr[g][0] = biasB[g * 1024 + j0 + cj];
      bsr[g][1] = biasB[g * 1024 + j0 + cj + 1];
    }
    float creg[2];
    if (cB0) {
      creg[0] = cB0[cb * 1024 + j0 + cj];
      creg[1] = cB0[cb * 1024 + j0 + cj + 1];
    } else {
      creg[0] = creg[1] = 0.f;
    }

    for (int d = 0; d <= 128; ++d) {
      if (d >= 1) {
        const int t = d - 1;
        f32x4 acc[4];
        acc[0] = 0; acc[1] = 0; acc[2] = 0; acc[3] = 0;
        // kw=0: k 0..1023 from RA[t]; kw=1: k 1024..2047 from hB (hB0 at t=0)
        const bf16* src = (kw == 0) ? (RA + (size_t)t * 65536)
                                    : ((t == 0) ? hB0 : (RB + (size_t)(t - 1) * 65536));
        if (src) {
          const bf16* ap = src + fr * 1024 + fk;
#pragma unroll 8
          for (int kk = 0; kk < 32; ++kk) {
            bf16x8 a0 = *(const bf16x8*)(ap + kk * 32);
            bf16x8 a1 = *(const bf16x8*)(ap + 16384 + kk * 32);
            bf16x8 a2 = *(const bf16x8*)(ap + 32768 + kk * 32);
            bf16x8 a3 = *(const bf16x8*)(ap + 49152 + kk * 32);
            bf16x8 w = as_bf16x8(bw[kk]);
            acc[0] = __builtin_amdgcn_mfma_f32_16x16x32_bf16(a0, w, acc[0], 0, 0, 0);
            acc[1] = __builtin_amdgcn_mfma_f32_16x16x32_bf16(a1, w, acc[1], 0, 0, 0);
            acc[2] = __builtin_amdgcn_mfma_f32_16x16x32_bf16(a2, w, acc[2], 0, 0, 0);
            acc[3] = __builtin_amdgcn_mfma_f32_16x16x32_bf16(a3, w, acc[3], 0, 0, 0);
          }
        }
#pragma unroll
        for (int bt = 0; bt < 4; ++bt)
#pragma unroll
          for (int r = 0; r < 4; ++r)
            gt[kw][bt * 16 + rq + r][ct * 16 + fr] = acc[bt][r];
        __syncthreads();

        float hn[2];
#pragma unroll
        for (int r = 0; r < 2; ++r) {
          int jj = cj + r;
          float gi = gt[0][cb][jj]      + gt[1][cb][jj]      + bsr[0][r];
          float gf = gt[0][cb][8 + jj]  + gt[1][cb][8 + jj]  + bsr[1][r];
          float gg = gt[0][cb][16 + jj] + gt[1][cb][16 + jj] + bsr[2][r];
          float go = gt[0][cb][24 + jj] + gt[1][cb][24 + jj] + bsr[3][r];
          float cn = sigf(gf) * creg[r] + sigf(gi) * tanhf(gg);
          creg[r] = cn;
          hn[r] = sigf(go) * tanhf(cn);
        }
        union { bf16 h[2]; unsigned u; } pk;
        pk.h[0] = (bf16)hn[0];
        pk.h[1] = (bf16)hn[1];
        __hip_atomic_store((unsigned*)(RB + (size_t)t * 65536 + cb * 1024 + j0 + cj),
                           pk.u, __ATOMIC_RELAXED, __HIP_MEMORY_SCOPE_AGENT);
        if (HfinB && t == 127) {
          bf16x2 e2; e2.x = (bf16)tanhf(hn[0]); e2.y = (bf16)tanhf(hn[1]);
          *(bf16x2*)(HfinB + cb * 1024 + j0 + cj) = e2;
        }
      }
      __syncthreads();
      if (tid == 0) {
        __hip_atomic_fetch_add(bar, 1u, __ATOMIC_RELAXED, __HIP_MEMORY_SCOPE_AGENT);
        const unsigned tgt = (unsigned)(d + 1) * 256u;
        while (__hip_atomic_load(bar, __ATOMIC_RELAXED, __HIP_MEMORY_SCOPE_AGENT) < tgt)
          __builtin_amdgcn_s_sleep(2);
      }
      __syncthreads();
    }
  }
}

// ---------------- host orchestration ----------------
extern "C" void kernel_launch(void* const* d_in, const int* in_sizes, int n_in,
                              void* d_out, int out_size, void* d_ws, size_t ws_size,
                              hipStream_t stream) {
  (void)in_sizes; (void)n_in; (void)out_size; (void)ws_size;
  const float* x      = (const float*)d_in[0];
  const float* dec_c0 = (const float*)d_in[1];
  const float* eWih0 = (const float*)d_in[2];
  const float* eWhh0 = (const float*)d_in[3];
  const float* eb0   = (const float*)d_in[4];
  const float* eWih1 = (const float*)d_in[5];
  const float* eWhh1 = (const float*)d_in[6];
  const float* eb1   = (const float*)d_in[7];
  const float* dWih0 = (const float*)d_in[8];
  const float* dWhh0 = (const float*)d_in[9];
  const float* db0   = (const float*)d_in[10];
  const float* dWih1 = (const float*)d_in[11];
  const float* dWhh1 = (const float*)d_in[12];
  const float* db1   = (const float*)d_in[13];
  const float* fcW   = (const float*)d_in[14];
  const float* fcb   = (const float*)d_in[15];
  float* out = (float*)d_out;

  const int H = 1024, I = 512, T = 128, B = 64;
  const int BH = B * H;
  const size_t TBI = (size_t)T * B * I;
  const size_t TBH = (size_t)T * B * H;

  char* p = (char*)d_ws;
  auto alloc = [&](size_t bytes) -> char* {
    char* r = p; p += (bytes + 255) & ~(size_t)255; return r;
  };
  bf16* Wih_e0 = (bf16*)alloc((size_t)4 * H * I * 2);
  bf16* Whh_e0 = (bf16*)alloc((size_t)4 * H * H * 2);
  bf16* Wcat_e1 = (bf16*)alloc((size_t)4 * H * 2 * H * 2);
  bf16* Wih_d0 = (bf16*)alloc((size_t)4 * H * I * 2);
  bf16* Whh_d0 = (bf16*)alloc((size_t)4 * H * H * 2);
  bf16* Wcat_d1 = (bf16*)alloc((size_t)4 * H * 2 * H * 2);
  bf16* Wfc = (bf16*)alloc((size_t)I * H * 2);
  bf16* xe = (bf16*)alloc(TBI * 2);
  bf16* xd = (bf16*)alloc(TBI * 2);
  bf16* G  = (bf16*)alloc((size_t)T * B * 4 * H * 2);   // 64 MB
  bf16* ring0 = (bf16*)alloc(TBH * 2);                  // layer-A ring
  bf16* ring1 = (bf16*)alloc(TBH * 2);                  // layer-B ring
  bf16* henc0 = (bf16*)alloc((size_t)BH * 2);
  bf16* henc1 = (bf16*)alloc((size_t)BH * 2);
  unsigned* bars = (unsigned*)alloc(256);

  prep_all_k<<<133120, 256, 0, stream>>>(x, eWih0, eWhh0, eWih1, eWhh1,
                                         dWih0, dWhh0, dWih1, dWhh1, fcW,
                                         Wih_e0, Whh_e0, Wcat_e1,
                                         Wih_d0, Whh_d0, Wcat_d1,
                                         Wfc, xe, xd, bars);

  auto coop = [&](const bf16* Gp, const bf16* WhhAp, const float* biasAp,
                  const bf16* hA0p, const float* cA0p, bf16* RAp,
                  const bf16* WcatBp, const float* biasBp, const bf16* hB0p,
                  const float* cB0p, bf16* RBp, bf16* HfA, bf16* HfB,
                  unsigned* barp) {
    void* args[] = { (void*)&Gp, (void*)&WhhAp, (void*)&biasAp, (void*)&hA0p,
                     (void*)&cA0p, (void*)&RAp, (void*)&WcatBp, (void*)&biasBp,
                     (void*)&hB0p, (void*)&cB0p, (void*)&RBp, (void*)&HfA,
                     (void*)&HfB, (void*)&barp };
    hipLaunchCooperativeKernel((void*)phase_k, dim3(256), dim3(256), args, 0, stream);
  };

  // ---- encoder: pre-GEMM (L0 input side) + persistent 2-layer phase ----
  gemm_bt_k<<<dim3(32, 64), 256, 0, stream>>>(xe, Wih_e0, G, nullptr, nullptr,
                                              8192, 4096, 512, 0);
  coop(G, Whh_e0, eb0, nullptr, nullptr, ring0,
       Wcat_e1, eb1, nullptr, nullptr, ring1, henc0, henc1, bars + 0);

  // ---- decoder: pre-GEMM (L0 input side) + persistent 2-layer phase ----
  gemm_bt_k<<<dim3(32, 64), 256, 0, stream>>>(xd, Wih_d0, G, nullptr, nullptr,
                                              8192, 4096, 512, 0);
  coop(G, Whh_d0, db0, henc0, dec_c0, ring0,
       Wcat_d1, db1, henc1, dec_c0 + BH, ring1, nullptr, nullptr, bars + 1);

  // ---- FC: sigmoid(ring1 @ fcW^T + fcb), permute [t,b]->[b,t] ----
  gemm_bt_k<<<dim3(4, 64), 256, 0, stream>>>(ring1, Wfc, nullptr, out, fcb,
                                             8192, 512, 1024, 1);
}

// Round 6
// 5366.018 us; speedup vs baseline: 1.5256x; 1.5256x over previous
//
#include <hip/hip_runtime.h>
#include <cmath>

typedef __bf16 bf16;
typedef float f32x4 __attribute__((ext_vector_type(4)));
typedef bf16 bf16x8 __attribute__((ext_vector_type(8)));
typedef bf16 bf16x2 __attribute__((ext_vector_type(2)));

#define DEVINL __device__ __forceinline__

DEVINL void gload_lds16(const void* g, void* l) {
  __builtin_amdgcn_global_load_lds(
      (const __attribute__((address_space(1))) void*)g,
      (__attribute__((address_space(3))) void*)l, 16, 0, 0);
}

DEVINL float sigf(float x) { return 1.f / (1.f + __expf(-x)); }

// ---------------- fused prep: weight casts + x prep + barrier zero ----------
__global__ void prep_all_k(
    const float* __restrict__ x,
    const float* __restrict__ eWih0, const float* __restrict__ eWhh0,
    const float* __restrict__ eWih1, const float* __restrict__ eWhh1,
    const float* __restrict__ dWih0, const float* __restrict__ dWhh0,
    const float* __restrict__ dWih1, const float* __restrict__ dWhh1,
    const float* __restrict__ fcW,
    bf16* __restrict__ Wih_e0, bf16* __restrict__ Whh_e0, bf16* __restrict__ Wcat_e1,
    bf16* __restrict__ Wih_d0, bf16* __restrict__ Whh_d0, bf16* __restrict__ Wcat_d1,
    bf16* __restrict__ Wfc, bf16* __restrict__ xe, bf16* __restrict__ xd,
    unsigned* __restrict__ bars) {
  if (blockIdx.x < 8) bars[blockIdx.x * 256 + threadIdx.x] = 0;
  int i = blockIdx.x * 256 + threadIdx.x;
  if (i < 2097152) { Wih_e0[i] = (bf16)eWih0[i]; return; }
  i -= 2097152;
  if (i < 4194304) { Whh_e0[i] = (bf16)eWhh0[i]; return; }
  i -= 4194304;
  if (i < 8388608) {
    int k = i & 2047, r = i >> 11;
    Wcat_e1[i] = (bf16)((k < 1024) ? eWih1[r * 1024 + k] : eWhh1[r * 1024 + k - 1024]);
    return;
  }
  i -= 8388608;
  if (i < 2097152) { Wih_d0[i] = (bf16)dWih0[i]; return; }
  i -= 2097152;
  if (i < 4194304) { Whh_d0[i] = (bf16)dWhh0[i]; return; }
  i -= 4194304;
  if (i < 8388608) {
    int k = i & 2047, r = i >> 11;
    Wcat_d1[i] = (bf16)((k < 1024) ? dWih1[r * 1024 + k] : dWhh1[r * 1024 + k - 1024]);
    return;
  }
  i -= 8388608;
  if (i < 524288) { Wfc[i] = (bf16)fcW[i]; return; }
  i -= 524288;
  if (i < 4194304) {
    int ii = i & 511;
    int b = (i >> 9) & 63;
    int t = i >> 15;
    xe[i] = (bf16)x[b * 65536 + t * 512 + ii];
    xd[i] = (t == 0) ? (bf16)0.f : (bf16)x[b * 65536 + (t - 1) * 512 + ii];
  }
}

// ---------------- big GEMM: C[M,N] = A[M,K] @ W[N,K]^T (bf16 in, f32 acc) ----------
__global__ __launch_bounds__(256) void gemm_bt_k(
    const bf16* __restrict__ A, const bf16* __restrict__ Bw,
    bf16* __restrict__ Cbf, float* __restrict__ Cf32, const float* __restrict__ bias,
    int M, int N, int K, int mode) {
  __shared__ __attribute__((aligned(16))) bf16 As[128 * 32];
  __shared__ __attribute__((aligned(16))) bf16 Bs[128 * 32];
  const int tid = threadIdx.x;
  const int lane = tid & 63;
  const int wave = tid >> 6;
  const int wm = wave >> 1, wn = wave & 1;
  const int m0 = blockIdx.y * 128;
  const int n0 = blockIdx.x * 128;

  f32x4 acc[4][4];
  for (int i = 0; i < 4; ++i)
    for (int j = 0; j < 4; ++j) acc[i][j] = 0;

  const int r1 = tid >> 2;
  const int kc = (tid & 3) * 8;
  const int fr = lane & 15;
  const int fk = (lane >> 4) * 8;

  for (int k0 = 0; k0 < K; k0 += 32) {
    gload_lds16(A + (size_t)(m0 + r1) * K + k0 + kc, As + tid * 8);
    gload_lds16(A + (size_t)(m0 + 64 + r1) * K + k0 + kc, As + 2048 + tid * 8);
    gload_lds16(Bw + (size_t)(n0 + r1) * K + k0 + kc, Bs + tid * 8);
    gload_lds16(Bw + (size_t)(n0 + 64 + r1) * K + k0 + kc, Bs + 2048 + tid * 8);
    __syncthreads();
    bf16x8 af[4], bw[4];
    for (int i = 0; i < 4; ++i)
      af[i] = *(const bf16x8*)(As + (wm * 64 + i * 16 + fr) * 32 + fk);
    for (int j = 0; j < 4; ++j)
      bw[j] = *(const bf16x8*)(Bs + (wn * 64 + j * 16 + fr) * 32 + fk);
    for (int i = 0; i < 4; ++i)
      for (int j = 0; j < 4; ++j)
        acc[i][j] = __builtin_amdgcn_mfma_f32_16x16x32_bf16(af[i], bw[j], acc[i][j], 0, 0, 0);
    __syncthreads();
  }

  const int col16 = lane & 15;
  const int rq = (lane >> 4) * 4;
  for (int i = 0; i < 4; ++i)
    for (int j = 0; j < 4; ++j)
      for (int r = 0; r < 4; ++r) {
        int row = m0 + wm * 64 + i * 16 + rq + r;
        int col = n0 + wn * 64 + j * 16 + col16;
        float v = acc[i][j][r];
        if (mode == 0) {
          Cbf[(size_t)row * N + col] = (bf16)v;
        } else {
          v = sigf(v + bias[col]);
          int b = row & 63, t = row >> 6;
          Cf32[(size_t)b * (128 * 512) + (size_t)t * 512 + col] = v;
        }
      }
}

// ---------------- persistent two-layer phase kernel (cooperative) ----------------
// 256 WGs x 256 thr, 1 WG/CU (LDS-bound). Weights LDS-RESIDENT: staged once
// before the step loop (R4/R5 showed the register allocator refuses to keep
// weight frags live across the loop -> per-step refetch was the 26us floor).
// LDS: weight tile (rows padded +8 elems -> ds_read_b128 2-way = free) + gt
// reduce buffer = 148480 B (dynamic shared, needs hipFuncSetAttribute).
// Barrier: 8 spread arrival counters (32 WGs each, separate cachelines) +
// WG0-published release word; all relaxed agent-scope atomics, no fences.
// h rings written once with 4B agent-scope atomic stores (coherence point),
// read next step with plain loads at fresh addresses (validated R4/R5).
__global__ __launch_bounds__(256, 1) void phase_k(
    const bf16* __restrict__ G, const bf16* __restrict__ WhhA,
    const float* __restrict__ biasA, const bf16* __restrict__ hA0,
    const float* __restrict__ cA0, bf16* __restrict__ RA,
    const bf16* __restrict__ WcatB, const float* __restrict__ biasB,
    const bf16* __restrict__ hB0, const float* __restrict__ cB0,
    bf16* __restrict__ RB, bf16* __restrict__ HfinA, bf16* __restrict__ HfinB,
    unsigned* __restrict__ bar) {
  extern __shared__ __attribute__((aligned(16))) char smem[];
  bf16* WS = (bf16*)smem;                       // weight tile (padded rows)
  float* gt = (float*)(smem + 131584);          // [2][64][33]
#define GT(kw, row, col) gt[(kw) * 2112 + (row) * 33 + (col)]

  const int tid = threadIdx.x;
  const int lane = tid & 63;
  const int wave = tid >> 6;
  const int ct = wave & 1;
  const int kw = wave >> 1;
  const int bid = blockIdx.x;
  const int half = bid >> 7;
  const int j0 = (bid & 127) * 8;
  const int fr = lane & 15;
  const int fk = (lane >> 4) * 8;
  const int rq = (lane >> 4) * 4;
  const int cb = tid >> 2;                      // cell batch
  const int cj = (tid & 3) * 2;                 // cell col pair

  const float* bias = half ? biasB : biasA;
  const float* c0 = half ? cB0 : cA0;

  float bsr[4][2];
#pragma unroll
  for (int g = 0; g < 4; ++g) {
    bsr[g][0] = bias[g * 1024 + j0 + cj];
    bsr[g][1] = bias[g * 1024 + j0 + cj + 1];
  }
  float creg[2];
  if (c0) {
    creg[0] = c0[cb * 1024 + j0 + cj];
    creg[1] = c0[cb * 1024 + j0 + cj + 1];
  } else {
    creg[0] = creg[1] = 0.f;
  }

  // ---- one-time weight staging into LDS ----
  {
    const int c = tid >> 3;                     // gate-col 0..31
    const int s = tid & 7;                      // segment
    const int nr = (c >> 3) * 1024 + j0 + (c & 7);
    if (half == 0) {
      const bf16* src = WhhA + (size_t)nr * 1024 + s * 128;
      bf16* dst = WS + c * 1032 + s * 128;
#pragma unroll
      for (int q = 0; q < 16; ++q)
        *(bf16x8*)(dst + q * 8) = *(const bf16x8*)(src + q * 8);
    } else {
      const bf16* src = WcatB + (size_t)nr * 2048 + s * 256;
      bf16* dst = WS + c * 2056 + s * 256;
#pragma unroll
      for (int q = 0; q < 32; ++q)
        *(bf16x8*)(dst + q * 8) = *(const bf16x8*)(src + q * 8);
    }
  }
  __syncthreads();

  const bf16* wsrow = (half == 0) ? (WS + (ct * 16 + fr) * 1032 + kw * 512 + fk)
                                  : (WS + (ct * 16 + fr) * 2056 + kw * 1024 + fk);

  for (int d = 0; d <= 128; ++d) {
    const int t = half ? (d - 1) : d;
    const bool active = half ? (d >= 1) : (d < 128);
    if (active) {
      f32x4 acc[4];
      acc[0] = 0; acc[1] = 0; acc[2] = 0; acc[3] = 0;
      float gx[4][2] = {{0, 0}, {0, 0}, {0, 0}, {0, 0}};

      if (half == 0) {
        const bf16* Gt = G + (size_t)t * 262144 + (size_t)cb * 4096;
#pragma unroll
        for (int g = 0; g < 4; ++g) {
          bf16x2 g2 = *(const bf16x2*)(Gt + g * 1024 + j0 + cj);
          gx[g][0] = (float)g2.x;
          gx[g][1] = (float)g2.y;
        }
        const bf16* hp = (t == 0) ? hA0 : (RA + (size_t)(t - 1) * 65536);
        if (hp) {
          const bf16* ap = hp + fr * 1024 + kw * 512 + fk;
#pragma unroll 8
          for (int kk = 0; kk < 16; ++kk) {
            bf16x8 w = *(const bf16x8*)(wsrow + kk * 32);
            bf16x8 a0 = *(const bf16x8*)(ap + kk * 32);
            bf16x8 a1 = *(const bf16x8*)(ap + 16384 + kk * 32);
            bf16x8 a2 = *(const bf16x8*)(ap + 32768 + kk * 32);
            bf16x8 a3 = *(const bf16x8*)(ap + 49152 + kk * 32);
            acc[0] = __builtin_amdgcn_mfma_f32_16x16x32_bf16(a0, w, acc[0], 0, 0, 0);
            acc[1] = __builtin_amdgcn_mfma_f32_16x16x32_bf16(a1, w, acc[1], 0, 0, 0);
            acc[2] = __builtin_amdgcn_mfma_f32_16x16x32_bf16(a2, w, acc[2], 0, 0, 0);
            acc[3] = __builtin_amdgcn_mfma_f32_16x16x32_bf16(a3, w, acc[3], 0, 0, 0);
          }
        }
      } else {
        // kw=0: k 0..1023 from RA[t]; kw=1: k 1024..2047 from hB (hB0 at t=0)
        const bf16* src = (kw == 0) ? (RA + (size_t)t * 65536)
                                    : ((t == 0) ? hB0 : (RB + (size_t)(t - 1) * 65536));
        if (src) {
          const bf16* ap = src + fr * 1024 + fk;
#pragma unroll 8
          for (int kk = 0; kk < 32; ++kk) {
            bf16x8 w = *(const bf16x8*)(wsrow + kk * 32);
            bf16x8 a0 = *(const bf16x8*)(ap + kk * 32);
            bf16x8 a1 = *(const bf16x8*)(ap + 16384 + kk * 32);
            bf16x8 a2 = *(const bf16x8*)(ap + 32768 + kk * 32);
            bf16x8 a3 = *(const bf16x8*)(ap + 49152 + kk * 32);
            acc[0] = __builtin_amdgcn_mfma_f32_16x16x32_bf16(a0, w, acc[0], 0, 0, 0);
            acc[1] = __builtin_amdgcn_mfma_f32_16x16x32_bf16(a1, w, acc[1], 0, 0, 0);
            acc[2] = __builtin_amdgcn_mfma_f32_16x16x32_bf16(a2, w, acc[2], 0, 0, 0);
            acc[3] = __builtin_amdgcn_mfma_f32_16x16x32_bf16(a3, w, acc[3], 0, 0, 0);
          }
        }
      }

#pragma unroll
      for (int bt = 0; bt < 4; ++bt)
#pragma unroll
        for (int r = 0; r < 4; ++r)
          GT(kw, bt * 16 + rq + r, ct * 16 + fr) = acc[bt][r];
      __syncthreads();

      float hn[2];
#pragma unroll
      for (int r = 0; r < 2; ++r) {
        int jj = cj + r;
        float gi = GT(0, cb, jj)      + GT(1, cb, jj)      + gx[0][r] + bsr[0][r];
        float gf = GT(0, cb, 8 + jj)  + GT(1, cb, 8 + jj)  + gx[1][r] + bsr[1][r];
        float gg = GT(0, cb, 16 + jj) + GT(1, cb, 16 + jj) + gx[2][r] + bsr[2][r];
        float go = GT(0, cb, 24 + jj) + GT(1, cb, 24 + jj) + gx[3][r] + bsr[3][r];
        float cn = sigf(gf) * creg[r] + sigf(gi) * tanhf(gg);
        creg[r] = cn;
        hn[r] = sigf(go) * tanhf(cn);
      }
      bf16* R = half ? RB : RA;
      union { bf16 h[2]; unsigned u; } pk;
      pk.h[0] = (bf16)hn[0];
      pk.h[1] = (bf16)hn[1];
      __hip_atomic_store((unsigned*)(R + (size_t)t * 65536 + cb * 1024 + j0 + cj),
                         pk.u, __ATOMIC_RELAXED, __HIP_MEMORY_SCOPE_AGENT);
      bf16* Hfin = half ? HfinB : HfinA;
      if (Hfin && t == 127) {
        bf16x2 e2; e2.x = (bf16)tanhf(hn[0]); e2.y = (bf16)tanhf(hn[1]);
        *(bf16x2*)(Hfin + cb * 1024 + j0 + cj) = e2;
      }
    }

    // ---- spread-arrival + release-broadcast grid barrier ----
    __syncthreads();  // drains vmcnt: h stores globally visible (write-through)
    if (bid == 0) {
      if (tid == 0)
        __hip_atomic_fetch_add(&bar[0], 1u, __ATOMIC_RELAXED, __HIP_MEMORY_SCOPE_AGENT);
      if (tid < 8) {
        const unsigned tgt = (unsigned)(d + 1) * 32u;
        while (__hip_atomic_load(&bar[tid * 32], __ATOMIC_RELAXED,
                                 __HIP_MEMORY_SCOPE_AGENT) < tgt)
          __builtin_amdgcn_s_sleep(2);
      }
      __syncthreads();
      if (tid == 0)
        __hip_atomic_store(&bar[256], (unsigned)(d + 1), __ATOMIC_RELAXED,
                           __HIP_MEMORY_SCOPE_AGENT);
    } else {
      if (tid == 0) {
        __hip_atomic_fetch_add(&bar[(bid & 7) * 32], 1u, __ATOMIC_RELAXED,
                               __HIP_MEMORY_SCOPE_AGENT);
        while (__hip_atomic_load(&bar[256], __ATOMIC_RELAXED,
                                 __HIP_MEMORY_SCOPE_AGENT) < (unsigned)(d + 1))
          __builtin_amdgcn_s_sleep(2);
      }
      __syncthreads();
    }
    __syncthreads();
  }
#undef GT
}

// ---------------- host orchestration ----------------
extern "C" void kernel_launch(void* const* d_in, const int* in_sizes, int n_in,
                              void* d_out, int out_size, void* d_ws, size_t ws_size,
                              hipStream_t stream) {
  (void)in_sizes; (void)n_in; (void)out_size; (void)ws_size;
  const float* x      = (const float*)d_in[0];
  const float* dec_c0 = (const float*)d_in[1];
  const float* eWih0 = (const float*)d_in[2];
  const float* eWhh0 = (const float*)d_in[3];
  const float* eb0   = (const float*)d_in[4];
  const float* eWih1 = (const float*)d_in[5];
  const float* eWhh1 = (const float*)d_in[6];
  const float* eb1   = (const float*)d_in[7];
  const float* dWih0 = (const float*)d_in[8];
  const float* dWhh0 = (const float*)d_in[9];
  const float* db0   = (const float*)d_in[10];
  const float* dWih1 = (const float*)d_in[11];
  const float* dWhh1 = (const float*)d_in[12];
  const float* db1   = (const float*)d_in[13];
  const float* fcW   = (const float*)d_in[14];
  const float* fcb   = (const float*)d_in[15];
  float* out = (float*)d_out;

  const int H = 1024, I = 512, T = 128, B = 64;
  const int BH = B * H;
  const size_t TBI = (size_t)T * B * I;
  const size_t TBH = (size_t)T * B * H;
  const int SMEM = 148480;  // 32*2056*2 (weights) + 2*64*33*4 (gt)

  char* p = (char*)d_ws;
  auto alloc = [&](size_t bytes) -> char* {
    char* r = p; p += (bytes + 255) & ~(size_t)255; return r;
  };
  bf16* Wih_e0 = (bf16*)alloc((size_t)4 * H * I * 2);
  bf16* Whh_e0 = (bf16*)alloc((size_t)4 * H * H * 2);
  bf16* Wcat_e1 = (bf16*)alloc((size_t)4 * H * 2 * H * 2);
  bf16* Wih_d0 = (bf16*)alloc((size_t)4 * H * I * 2);
  bf16* Whh_d0 = (bf16*)alloc((size_t)4 * H * H * 2);
  bf16* Wcat_d1 = (bf16*)alloc((size_t)4 * H * 2 * H * 2);
  bf16* Wfc = (bf16*)alloc((size_t)I * H * 2);
  bf16* xe = (bf16*)alloc(TBI * 2);
  bf16* xd = (bf16*)alloc(TBI * 2);
  bf16* G  = (bf16*)alloc((size_t)T * B * 4 * H * 2);   // 64 MB
  bf16* ring0 = (bf16*)alloc(TBH * 2);                  // layer-A ring
  bf16* ring1 = (bf16*)alloc(TBH * 2);                  // layer-B ring
  bf16* henc0 = (bf16*)alloc((size_t)BH * 2);
  bf16* henc1 = (bf16*)alloc((size_t)BH * 2);
  unsigned* bars = (unsigned*)alloc(8192);

  hipFuncSetAttribute((const void*)phase_k,
                      hipFuncAttributeMaxDynamicSharedMemorySize, SMEM);

  prep_all_k<<<133120, 256, 0, stream>>>(x, eWih0, eWhh0, eWih1, eWhh1,
                                         dWih0, dWhh0, dWih1, dWhh1, fcW,
                                         Wih_e0, Whh_e0, Wcat_e1,
                                         Wih_d0, Whh_d0, Wcat_d1,
                                         Wfc, xe, xd, bars);

  auto coop = [&](const bf16* Gp, const bf16* WhhAp, const float* biasAp,
                  const bf16* hA0p, const float* cA0p, bf16* RAp,
                  const bf16* WcatBp, const float* biasBp, const bf16* hB0p,
                  const float* cB0p, bf16* RBp, bf16* HfA, bf16* HfB,
                  unsigned* barp) {
    void* args[] = { (void*)&Gp, (void*)&WhhAp, (void*)&biasAp, (void*)&hA0p,
                     (void*)&cA0p, (void*)&RAp, (void*)&WcatBp, (void*)&biasBp,
                     (void*)&hB0p, (void*)&cB0p, (void*)&RBp, (void*)&HfA,
                     (void*)&HfB, (void*)&barp };
    hipLaunchCooperativeKernel((void*)phase_k, dim3(256), dim3(256), args,
                               SMEM, stream);
  };

  // ---- encoder: pre-GEMM (L0 input side) + persistent 2-layer phase ----
  gemm_bt_k<<<dim3(32, 64), 256, 0, stream>>>(xe, Wih_e0, G, nullptr, nullptr,
                                              8192, 4096, 512, 0);
  coop(G, Whh_e0, eb0, nullptr, nullptr, ring0,
       Wcat_e1, eb1, nullptr, nullptr, ring1, henc0, henc1, bars + 0);

  // ---- decoder: pre-GEMM (L0 input side) + persistent 2-layer phase ----
  gemm_bt_k<<<dim3(32, 64), 256, 0, stream>>>(xd, Wih_d0, G, nullptr, nullptr,
                                              8192, 4096, 512, 0);
  coop(G, Whh_d0, db0, henc0, dec_c0, ring0,
       Wcat_d1, db1, henc1, dec_c0 + BH, ring1, nullptr, nullptr, bars + 512);

  // ---- FC: sigmoid(ring1 @ fcW^T + fcb), permute [t,b]->[b,t] ----
  gemm_bt_k<<<dim3(4, 64), 256, 0, stream>>>(ring1, Wfc, nullptr, out, fcb,
                                             8192, 512, 1024, 1);
}

// Round 7
// 3763.042 us; speedup vs baseline: 2.1754x; 1.4260x over previous
//
#include <hip/hip_runtime.h>
#include <cmath>

typedef __bf16 bf16;
typedef float f32x4 __attribute__((ext_vector_type(4)));
typedef bf16 bf16x8 __attribute__((ext_vector_type(8)));
typedef bf16 bf16x2 __attribute__((ext_vector_type(2)));

#define DEVINL __device__ __forceinline__

DEVINL void gload_lds16(const void* g, void* l) {
  __builtin_amdgcn_global_load_lds(
      (const __attribute__((address_space(1))) void*)g,
      (__attribute__((address_space(3))) void*)l, 16, 0, 0);
}

DEVINL float sigf(float x) { return 1.f / (1.f + __expf(-x)); }

#define MFMA __builtin_amdgcn_mfma_f32_16x16x32_bf16

// ---------------- fused prep: weight casts + x prep + barrier zero ----------
__global__ void prep_all_k(
    const float* __restrict__ x,
    const float* __restrict__ eWih0, const float* __restrict__ eWhh0,
    const float* __restrict__ eWih1, const float* __restrict__ eWhh1,
    const float* __restrict__ dWih0, const float* __restrict__ dWhh0,
    const float* __restrict__ dWih1, const float* __restrict__ dWhh1,
    const float* __restrict__ fcW,
    bf16* __restrict__ Wih_e0, bf16* __restrict__ Whh_e0, bf16* __restrict__ Wcat_e1,
    bf16* __restrict__ Wih_d0, bf16* __restrict__ Whh_d0, bf16* __restrict__ Wcat_d1,
    bf16* __restrict__ Wfc, bf16* __restrict__ xe, bf16* __restrict__ xd,
    unsigned* __restrict__ bars) {
  if (blockIdx.x < 8) bars[blockIdx.x * 256 + threadIdx.x] = 0;
  int i = blockIdx.x * 256 + threadIdx.x;
  if (i < 2097152) { Wih_e0[i] = (bf16)eWih0[i]; return; }
  i -= 2097152;
  if (i < 4194304) { Whh_e0[i] = (bf16)eWhh0[i]; return; }
  i -= 4194304;
  if (i < 8388608) {
    int k = i & 2047, r = i >> 11;
    Wcat_e1[i] = (bf16)((k < 1024) ? eWih1[r * 1024 + k] : eWhh1[r * 1024 + k - 1024]);
    return;
  }
  i -= 8388608;
  if (i < 2097152) { Wih_d0[i] = (bf16)dWih0[i]; return; }
  i -= 2097152;
  if (i < 4194304) { Whh_d0[i] = (bf16)dWhh0[i]; return; }
  i -= 4194304;
  if (i < 8388608) {
    int k = i & 2047, r = i >> 11;
    Wcat_d1[i] = (bf16)((k < 1024) ? dWih1[r * 1024 + k] : dWhh1[r * 1024 + k - 1024]);
    return;
  }
  i -= 8388608;
  if (i < 524288) { Wfc[i] = (bf16)fcW[i]; return; }
  i -= 524288;
  if (i < 4194304) {
    int ii = i & 511;
    int b = (i >> 9) & 63;
    int t = i >> 15;
    xe[i] = (bf16)x[b * 65536 + t * 512 + ii];
    xd[i] = (t == 0) ? (bf16)0.f : (bf16)x[b * 65536 + (t - 1) * 512 + ii];
  }
}

// ---------------- big GEMM: C[M,N] = A[M,K] @ W[N,K]^T (bf16 in, f32 acc) ----------
__global__ __launch_bounds__(256) void gemm_bt_k(
    const bf16* __restrict__ A, const bf16* __restrict__ Bw,
    bf16* __restrict__ Cbf, float* __restrict__ Cf32, const float* __restrict__ bias,
    int M, int N, int K, int mode) {
  __shared__ __attribute__((aligned(16))) bf16 As[128 * 32];
  __shared__ __attribute__((aligned(16))) bf16 Bs[128 * 32];
  const int tid = threadIdx.x;
  const int lane = tid & 63;
  const int wave = tid >> 6;
  const int wm = wave >> 1, wn = wave & 1;
  const int m0 = blockIdx.y * 128;
  const int n0 = blockIdx.x * 128;

  f32x4 acc[4][4];
  for (int i = 0; i < 4; ++i)
    for (int j = 0; j < 4; ++j) acc[i][j] = 0;

  const int r1 = tid >> 2;
  const int kc = (tid & 3) * 8;
  const int fr = lane & 15;
  const int fk = (lane >> 4) * 8;

  for (int k0 = 0; k0 < K; k0 += 32) {
    gload_lds16(A + (size_t)(m0 + r1) * K + k0 + kc, As + tid * 8);
    gload_lds16(A + (size_t)(m0 + 64 + r1) * K + k0 + kc, As + 2048 + tid * 8);
    gload_lds16(Bw + (size_t)(n0 + r1) * K + k0 + kc, Bs + tid * 8);
    gload_lds16(Bw + (size_t)(n0 + 64 + r1) * K + k0 + kc, Bs + 2048 + tid * 8);
    __syncthreads();
    bf16x8 af[4], bw[4];
    for (int i = 0; i < 4; ++i)
      af[i] = *(const bf16x8*)(As + (wm * 64 + i * 16 + fr) * 32 + fk);
    for (int j = 0; j < 4; ++j)
      bw[j] = *(const bf16x8*)(Bs + (wn * 64 + j * 16 + fr) * 32 + fk);
    for (int i = 0; i < 4; ++i)
      for (int j = 0; j < 4; ++j)
        acc[i][j] = MFMA(af[i], bw[j], acc[i][j], 0, 0, 0);
    __syncthreads();
  }

  const int col16 = lane & 15;
  const int rq = (lane >> 4) * 4;
  for (int i = 0; i < 4; ++i)
    for (int j = 0; j < 4; ++j)
      for (int r = 0; r < 4; ++r) {
        int row = m0 + wm * 64 + i * 16 + rq + r;
        int col = n0 + wn * 64 + j * 16 + col16;
        float v = acc[i][j][r];
        if (mode == 0) {
          Cbf[(size_t)row * N + col] = (bf16)v;
        } else {
          v = sigf(v + bias[col]);
          int b = row & 63, t = row >> 6;
          Cf32[(size_t)b * (128 * 512) + (size_t)t * 512 + col] = v;
        }
      }
}

// ---------------- persistent two-layer phase kernel (cooperative) ----------------
// 256 WGs x 256 thr, 1 WG/CU. Weights LDS-resident (R6 win). NEW in R7:
//  - waves own K-QUARTERS (all 32 gate-cols each): no A-operand duplication
//    (R6's ct waves read identical data twice); gt reduce = 2 rounds.
//  - explicit double-buffered A-load pipeline ab[2][16]: 16 loads in flight.
//  - replicated release words: 8 lines x 32 pollers (was 1 x 255).
__global__ __launch_bounds__(256, 1) void phase_k(
    const bf16* __restrict__ G, const bf16* __restrict__ WhhA,
    const float* __restrict__ biasA, const bf16* __restrict__ hA0,
    const float* __restrict__ cA0, bf16* __restrict__ RA,
    const bf16* __restrict__ WcatB, const float* __restrict__ biasB,
    const bf16* __restrict__ hB0, const float* __restrict__ cB0,
    bf16* __restrict__ RB, bf16* __restrict__ HfinA, bf16* __restrict__ HfinB,
    unsigned* __restrict__ bar) {
  extern __shared__ __attribute__((aligned(16))) char smem[];
  bf16* WS = (bf16*)smem;                       // weight tile, padded rows
  float* gt = (float*)(smem + 131584);          // [2][64][33]
#define GT(h, row, col) gt[(h) * 2112 + (row) * 33 + (col)]

  const int tid = threadIdx.x;
  const int lane = tid & 63;
  const int q = tid >> 6;                       // wave = K-quarter 0..3
  const int bid = blockIdx.x;
  const int half = bid >> 7;
  const int j0 = (bid & 127) * 8;
  const int fr = lane & 15;
  const int fk = (lane >> 4) * 8;
  const int rq = (lane >> 4) * 4;
  const int cb = tid >> 2;                      // cell batch
  const int cj = (tid & 3) * 2;                 // cell col pair

  const float* bias = half ? biasB : biasA;
  const float* c0 = half ? cB0 : cA0;
  const int RS = half ? 2056 : 1032;            // LDS weight row stride (elems)
  const int KQ = half ? 512 : 256;              // K quarter width

  float bsr[4][2];
#pragma unroll
  for (int g = 0; g < 4; ++g) {
    bsr[g][0] = bias[g * 1024 + j0 + cj];
    bsr[g][1] = bias[g * 1024 + j0 + cj + 1];
  }
  float creg[2];
  if (c0) {
    creg[0] = c0[cb * 1024 + j0 + cj];
    creg[1] = c0[cb * 1024 + j0 + cj + 1];
  } else {
    creg[0] = creg[1] = 0.f;
  }

  // ---- one-time weight staging into LDS ----
  {
    const int c = tid >> 3;                     // gate-col 0..31
    const int s = tid & 7;                      // segment
    const int nr = (c >> 3) * 1024 + j0 + (c & 7);
    if (half == 0) {
      const bf16* src = WhhA + (size_t)nr * 1024 + s * 128;
      bf16* dst = WS + c * 1032 + s * 128;
#pragma unroll
      for (int w = 0; w < 16; ++w)
        *(bf16x8*)(dst + w * 8) = *(const bf16x8*)(src + w * 8);
    } else {
      const bf16* src = WcatB + (size_t)nr * 2048 + s * 256;
      bf16* dst = WS + c * 2056 + s * 256;
#pragma unroll
      for (int w = 0; w < 32; ++w)
        *(bf16x8*)(dst + w * 8) = *(const bf16x8*)(src + w * 8);
    }
  }
  __syncthreads();

  const bf16* wsc0 = WS + fr * RS + q * KQ + fk;          // cols 0..15
  const bf16* wsc1 = WS + (16 + fr) * RS + q * KQ + fk;   // cols 16..31

  for (int d = 0; d <= 128; ++d) {
    const int t = half ? (d - 1) : d;
    const bool active = half ? (d >= 1) : (d < 128);
    if (active) {
      f32x4 acc[8];   // [bt*2 + c]
#pragma unroll
      for (int i = 0; i < 8; ++i) acc[i] = 0;
      float gx[4][2] = {{0, 0}, {0, 0}, {0, 0}, {0, 0}};

      const bf16* src;
      int colbase;
      if (half == 0) {
        const bf16* Gt = G + (size_t)t * 262144 + (size_t)cb * 4096;
#pragma unroll
        for (int g = 0; g < 4; ++g) {
          bf16x2 g2 = *(const bf16x2*)(Gt + g * 1024 + j0 + cj);
          gx[g][0] = (float)g2.x;
          gx[g][1] = (float)g2.y;
        }
        src = (t == 0) ? hA0 : (RA + (size_t)(t - 1) * 65536);
        colbase = q * 256;
      } else {
        // q 0,1 -> RA[t] halves; q 2,3 -> own h (hB0 at t=0, else RB[t-1])
        src = (q < 2) ? (RA + (size_t)t * 65536)
                      : ((t == 0) ? hB0 : (RB + (size_t)(t - 1) * 65536));
        colbase = (q & 1) * 512;
      }

      if (src) {
        const bf16* ap = src + colbase + fk;
        const int NB = half ? 4 : 2;            // blocks of 4 kk
        bf16x8 ab[2][16];
        // prologue: block 0 (16 back-to-back independent loads)
#pragma unroll
        for (int bt = 0; bt < 4; ++bt)
#pragma unroll
          for (int kk = 0; kk < 4; ++kk)
            ab[0][bt * 4 + kk] = *(const bf16x8*)(ap + (bt * 16 + fr) * 1024 + kk * 32);
#pragma unroll
        for (int blk = 0; blk < 4; ++blk) {
          if (blk >= NB) break;
          if (blk + 1 < NB) {
#pragma unroll
            for (int bt = 0; bt < 4; ++bt)
#pragma unroll
              for (int kk = 0; kk < 4; ++kk)
                ab[(blk + 1) & 1][bt * 4 + kk] =
                    *(const bf16x8*)(ap + (bt * 16 + fr) * 1024 + (blk + 1) * 128 + kk * 32);
          }
#pragma unroll
          for (int kk = 0; kk < 4; ++kk) {
            bf16x8 w0 = *(const bf16x8*)(wsc0 + blk * 128 + kk * 32);
            bf16x8 w1 = *(const bf16x8*)(wsc1 + blk * 128 + kk * 32);
#pragma unroll
            for (int bt = 0; bt < 4; ++bt) {
              acc[bt * 2 + 0] = MFMA(ab[blk & 1][bt * 4 + kk], w0, acc[bt * 2 + 0], 0, 0, 0);
              acc[bt * 2 + 1] = MFMA(ab[blk & 1][bt * 4 + kk], w1, acc[bt * 2 + 1], 0, 0, 0);
            }
          }
        }
      }

      // ---- two-round k-quarter reduce in LDS ----
      if (q < 2) {
#pragma unroll
        for (int bt = 0; bt < 4; ++bt)
#pragma unroll
          for (int c = 0; c < 2; ++c)
#pragma unroll
            for (int r = 0; r < 4; ++r)
              GT(q, bt * 16 + rq + r, c * 16 + fr) = acc[bt * 2 + c][r];
      }
      __syncthreads();
      if (q >= 2) {
#pragma unroll
        for (int bt = 0; bt < 4; ++bt)
#pragma unroll
          for (int c = 0; c < 2; ++c)
#pragma unroll
            for (int r = 0; r < 4; ++r)
              GT(q - 2, bt * 16 + rq + r, c * 16 + fr) += acc[bt * 2 + c][r];
      }
      __syncthreads();

      float hn[2];
#pragma unroll
      for (int r = 0; r < 2; ++r) {
        int jj = cj + r;
        float gi = GT(0, cb, jj)      + GT(1, cb, jj)      + gx[0][r] + bsr[0][r];
        float gf = GT(0, cb, 8 + jj)  + GT(1, cb, 8 + jj)  + gx[1][r] + bsr[1][r];
        float gg = GT(0, cb, 16 + jj) + GT(1, cb, 16 + jj) + gx[2][r] + bsr[2][r];
        float go = GT(0, cb, 24 + jj) + GT(1, cb, 24 + jj) + gx[3][r] + bsr[3][r];
        float cn = sigf(gf) * creg[r] + sigf(gi) * tanhf(gg);
        creg[r] = cn;
        hn[r] = sigf(go) * tanhf(cn);
      }
      bf16* R = half ? RB : RA;
      union { bf16 h[2]; unsigned u; } pk;
      pk.h[0] = (bf16)hn[0];
      pk.h[1] = (bf16)hn[1];
      __hip_atomic_store((unsigned*)(R + (size_t)t * 65536 + cb * 1024 + j0 + cj),
                         pk.u, __ATOMIC_RELAXED, __HIP_MEMORY_SCOPE_AGENT);
      bf16* Hfin = half ? HfinB : HfinA;
      if (Hfin && t == 127) {
        bf16x2 e2; e2.x = (bf16)tanhf(hn[0]); e2.y = (bf16)tanhf(hn[1]);
        *(bf16x2*)(Hfin + cb * 1024 + j0 + cj) = e2;
      }
    }

    // ---- grid barrier: spread arrivals (8 lines) + replicated release (8) ----
    __syncthreads();  // drains vmcnt: h stores at coherence point
    if (bid == 0) {
      if (tid == 0)
        __hip_atomic_fetch_add(&bar[0], 1u, __ATOMIC_RELAXED, __HIP_MEMORY_SCOPE_AGENT);
      if (tid < 8) {
        const unsigned tgt = (unsigned)(d + 1) * 32u;
        while (__hip_atomic_load(&bar[tid * 32], __ATOMIC_RELAXED,
                                 __HIP_MEMORY_SCOPE_AGENT) < tgt)
          __builtin_amdgcn_s_sleep(2);
      }
      __syncthreads();
      if (tid < 8)
        __hip_atomic_store(&bar[256 + tid * 32], (unsigned)(d + 1), __ATOMIC_RELAXED,
                           __HIP_MEMORY_SCOPE_AGENT);
    } else {
      if (tid == 0) {
        __hip_atomic_fetch_add(&bar[(bid & 7) * 32], 1u, __ATOMIC_RELAXED,
                               __HIP_MEMORY_SCOPE_AGENT);
        while (__hip_atomic_load(&bar[256 + (bid & 7) * 32], __ATOMIC_RELAXED,
                                 __HIP_MEMORY_SCOPE_AGENT) < (unsigned)(d + 1))
          __builtin_amdgcn_s_sleep(4);
      }
      __syncthreads();
    }
  }
#undef GT
}

// ---------------- host orchestration ----------------
extern "C" void kernel_launch(void* const* d_in, const int* in_sizes, int n_in,
                              void* d_out, int out_size, void* d_ws, size_t ws_size,
                              hipStream_t stream) {
  (void)in_sizes; (void)n_in; (void)out_size; (void)ws_size;
  const float* x      = (const float*)d_in[0];
  const float* dec_c0 = (const float*)d_in[1];
  const float* eWih0 = (const float*)d_in[2];
  const float* eWhh0 = (const float*)d_in[3];
  const float* eb0   = (const float*)d_in[4];
  const float* eWih1 = (const float*)d_in[5];
  const float* eWhh1 = (const float*)d_in[6];
  const float* eb1   = (const float*)d_in[7];
  const float* dWih0 = (const float*)d_in[8];
  const float* dWhh0 = (const float*)d_in[9];
  const float* db0   = (const float*)d_in[10];
  const float* dWih1 = (const float*)d_in[11];
  const float* dWhh1 = (const float*)d_in[12];
  const float* db1   = (const float*)d_in[13];
  const float* fcW   = (const float*)d_in[14];
  const float* fcb   = (const float*)d_in[15];
  float* out = (float*)d_out;

  const int H = 1024, I = 512, T = 128, B = 64;
  const int BH = B * H;
  const size_t TBI = (size_t)T * B * I;
  const size_t TBH = (size_t)T * B * H;
  const int SMEM = 148480;  // 32*2056*2 (weights) + 2*64*33*4 (gt)

  char* p = (char*)d_ws;
  auto alloc = [&](size_t bytes) -> char* {
    char* r = p; p += (bytes + 255) & ~(size_t)255; return r;
  };
  bf16* Wih_e0 = (bf16*)alloc((size_t)4 * H * I * 2);
  bf16* Whh_e0 = (bf16*)alloc((size_t)4 * H * H * 2);
  bf16* Wcat_e1 = (bf16*)alloc((size_t)4 * H * 2 * H * 2);
  bf16* Wih_d0 = (bf16*)alloc((size_t)4 * H * I * 2);
  bf16* Whh_d0 = (bf16*)alloc((size_t)4 * H * H * 2);
  bf16* Wcat_d1 = (bf16*)alloc((size_t)4 * H * 2 * H * 2);
  bf16* Wfc = (bf16*)alloc((size_t)I * H * 2);
  bf16* xe = (bf16*)alloc(TBI * 2);
  bf16* xd = (bf16*)alloc(TBI * 2);
  bf16* G  = (bf16*)alloc((size_t)T * B * 4 * H * 2);   // 64 MB
  bf16* ring0 = (bf16*)alloc(TBH * 2);                  // layer-A ring
  bf16* ring1 = (bf16*)alloc(TBH * 2);                  // layer-B ring
  bf16* henc0 = (bf16*)alloc((size_t)BH * 2);
  bf16* henc1 = (bf16*)alloc((size_t)BH * 2);
  unsigned* bars = (unsigned*)alloc(8192);

  hipFuncSetAttribute((const void*)phase_k,
                      hipFuncAttributeMaxDynamicSharedMemorySize, SMEM);

  prep_all_k<<<133120, 256, 0, stream>>>(x, eWih0, eWhh0, eWih1, eWhh1,
                                         dWih0, dWhh0, dWih1, dWhh1, fcW,
                                         Wih_e0, Whh_e0, Wcat_e1,
                                         Wih_d0, Whh_d0, Wcat_d1,
                                         Wfc, xe, xd, bars);

  auto coop = [&](const bf16* Gp, const bf16* WhhAp, const float* biasAp,
                  const bf16* hA0p, const float* cA0p, bf16* RAp,
                  const bf16* WcatBp, const float* biasBp, const bf16* hB0p,
                  const float* cB0p, bf16* RBp, bf16* HfA, bf16* HfB,
                  unsigned* barp) {
    void* args[] = { (void*)&Gp, (void*)&WhhAp, (void*)&biasAp, (void*)&hA0p,
                     (void*)&cA0p, (void*)&RAp, (void*)&WcatBp, (void*)&biasBp,
                     (void*)&hB0p, (void*)&cB0p, (void*)&RBp, (void*)&HfA,
                     (void*)&HfB, (void*)&barp };
    hipLaunchCooperativeKernel((void*)phase_k, dim3(256), dim3(256), args,
                               SMEM, stream);
  };

  // ---- encoder: pre-GEMM (L0 input side) + persistent 2-layer phase ----
  gemm_bt_k<<<dim3(32, 64), 256, 0, stream>>>(xe, Wih_e0, G, nullptr, nullptr,
                                              8192, 4096, 512, 0);
  coop(G, Whh_e0, eb0, nullptr, nullptr, ring0,
       Wcat_e1, eb1, nullptr, nullptr, ring1, henc0, henc1, bars + 0);

  // ---- decoder: pre-GEMM (L0 input side) + persistent 2-layer phase ----
  gemm_bt_k<<<dim3(32, 64), 256, 0, stream>>>(xd, Wih_d0, G, nullptr, nullptr,
                                              8192, 4096, 512, 0);
  coop(G, Whh_d0, db0, henc0, dec_c0, ring0,
       Wcat_d1, db1, henc1, dec_c0 + BH, ring1, nullptr, nullptr, bars + 512);

  // ---- FC: sigmoid(ring1 @ fcW^T + fcb), permute [t,b]->[b,t] ----
  gemm_bt_k<<<dim3(4, 64), 256, 0, stream>>>(ring1, Wfc, nullptr, out, fcb,
                                             8192, 512, 1024, 1);
}